// Round 3
// baseline (205.482 us; speedup 1.0000x reference)
//
#include <hip/hip_runtime.h>
#include <hip/hip_bf16.h>
#include <cstddef>

namespace {
constexpr int B  = 2;
constexpr int Z  = 200;
constexpr int X  = 200;
constexpr int C  = 128;
constexpr int H  = 4;
constexpr int P  = 8;
constexpr int N  = Z * X;       // 40000
constexpr int BN = B * N;       // 80000
constexpr int SC = 96;          // proj_s cols: 64 offsets (f32) + 32 softmax'd weights (f32)
constexpr int NF_P = 14;        // 224/16 output fragments (proj GEMM)
constexpr int NF_O = 8;         // 128/16 output fragments (out GEMM)
constexpr int KS   = 4;         // 128/32 K-steps

typedef __attribute__((ext_vector_type(8))) short short8;
typedef __attribute__((ext_vector_type(4))) float f32x4;

__device__ inline ushort f2bf(float x) {
    __hip_bfloat16 h = __float2bfloat16(x);
    return *reinterpret_cast<ushort*>(&h);
}
__device__ inline float bflo(unsigned u) { return __uint_as_float(u << 16); }
__device__ inline float bfhi(unsigned u) { return __uint_as_float(u & 0xffff0000u); }
__device__ inline unsigned packbf(float a, float b) {
    return (unsigned)f2bf(a) | ((unsigned)f2bf(b) << 16);
}
// single-instruction lane xor-shuffles (BitMode ds_swizzle), masks 1/2/4
template <int MASK>
__device__ inline float swzx(float x) {
    constexpr int pat = (MASK << 10) | 0x1F;
    return __int_as_float(__builtin_amdgcn_ds_swizzle(__float_as_int(x), pat));
}
}

// ---------------------------------------------------------------------------
// Prep: pack weights into MFMA B-fragment order wt[ks][f][lane][8 bf16],
// k = ks*32 + (l>>4)*8 + e, n = f*16 + (l&15). Also folds W12 = Wout1@Wout2,
// biasp[224], b12[128].
// ---------------------------------------------------------------------------
__global__ __launch_bounds__(256) void vsa_k_prep(
    const float* __restrict__ Wv,    const float* __restrict__ bv,
    const float* __restrict__ Woff,  const float* __restrict__ boff,
    const float* __restrict__ Wattn, const float* __restrict__ battn,
    const float* __restrict__ Wout1, const float* __restrict__ bout1,
    const float* __restrict__ Wout2, const float* __restrict__ bout2,
    ushort* __restrict__ wtp, ushort* __restrict__ wtp2,
    float* __restrict__ biasp, float* __restrict__ bias2)
{
    const int u = blockIdx.x * 256 + threadIdx.x;
    constexpr int NP = KS * NF_P * 64;   // 3584
    constexpr int NO = KS * NF_O * 64;   // 2048

    if (u < NP) {
        int ks  = u / (NF_P * 64);
        int rem = u - ks * (NF_P * 64);
        int f = rem >> 6, l = rem & 63;
        int n  = f * 16 + (l & 15);
        int kb = ks * 32 + (l >> 4) * 8;
        float v[8];
        #pragma unroll
        for (int e = 0; e < 8; ++e) {
            int k = kb + e;
            if (n < 128)      v[e] = Wv[k * 128 + n];
            else if (n < 192) v[e] = Woff[k * 64 + (n - 128)];
            else              v[e] = Wattn[k * 32 + (n - 192)];
        }
        unsigned* dst = (unsigned*)(wtp + (size_t)u * 8);
        #pragma unroll
        for (int i = 0; i < 4; ++i) dst[i] = packbf(v[2*i], v[2*i+1]);
    } else if (u < NP + NO) {
        int t   = u - NP;
        int ks  = t / (NF_O * 64);
        int rem = t - ks * (NF_O * 64);
        int f = rem >> 6, l = rem & 63;
        int n  = f * 16 + (l & 15);
        int kb = ks * 32 + (l >> 4) * 8;
        float acc[8] = {0,0,0,0,0,0,0,0};
        for (int j = 0; j < 128; ++j) {
            float w2 = Wout2[j * 128 + n];
            #pragma unroll
            for (int e = 0; e < 8; ++e)
                acc[e] = fmaf(Wout1[(kb + e) * 128 + j], w2, acc[e]);
        }
        unsigned* dst = (unsigned*)(wtp2 + (size_t)t * 8);
        #pragma unroll
        for (int i = 0; i < 4; ++i) dst[i] = packbf(acc[2*i], acc[2*i+1]);
    } else if (u < NP + NO + 224) {
        int c = u - NP - NO;
        float bb;
        if (c < 128)      bb = bv[c];
        else if (c < 192) bb = boff[c - 128];
        else              bb = battn[c - 192];
        biasp[c] = bb;
    } else if (u < NP + NO + 224 + 128) {
        int c = u - NP - NO - 224;
        float acc = bout2[c];
        for (int j = 0; j < 128; ++j)
            acc = fmaf(bout1[j], Wout2[j * 128 + c], acc);
        bias2[c] = acc;
    }
}

// ---------------------------------------------------------------------------
// Fused projection GEMM (MFMA, no LDS) + softmax epilogue.
//   cols 0..127   -> proj_v (bf16 values)
//   cols 128..191 -> proj_s[row][0..63]  (f32 offsets)
//   cols 192..223 -> softmax over each 8-point group (lanes m&7 via xor
//                    ds_swizzle 1/2/4) -> proj_s[row][64..95] (f32 weights)
// ---------------------------------------------------------------------------
__global__ __launch_bounds__(256) void vsa_k_proj(
    const float* __restrict__ Q, const ushort* __restrict__ wtp,
    const float* __restrict__ biasp,
    ushort* __restrict__ proj_v, float* __restrict__ proj_s)
{
    const int lane = threadIdx.x & 63;
    const int wave = blockIdx.x * 4 + (threadIdx.x >> 6);
    const int row0 = wave * 16;
    const int m  = lane & 15;
    const int kg = lane >> 4;

    const float* qp = Q + (size_t)(row0 + m) * 128 + kg * 8;

    f32x4 acc[NF_P];
    #pragma unroll
    for (int f = 0; f < NF_P; ++f) acc[f] = (f32x4){0.f, 0.f, 0.f, 0.f};

    #pragma unroll
    for (int ks = 0; ks < KS; ++ks) {
        float4 a0 = *(const float4*)(qp + ks * 32);
        float4 a1 = *(const float4*)(qp + ks * 32 + 4);
        short8 af;
        af[0] = (short)f2bf(a0.x); af[1] = (short)f2bf(a0.y);
        af[2] = (short)f2bf(a0.z); af[3] = (short)f2bf(a0.w);
        af[4] = (short)f2bf(a1.x); af[5] = (short)f2bf(a1.y);
        af[6] = (short)f2bf(a1.z); af[7] = (short)f2bf(a1.w);
        const short8* wrow = (const short8*)wtp + ks * NF_P * 64 + lane;
        #pragma unroll
        for (int f = 0; f < NF_P; ++f)
            acc[f] = __builtin_amdgcn_mfma_f32_16x16x32_bf16(af, wrow[f * 64], acc[f], 0, 0, 0);
    }

    // values -> bf16
    #pragma unroll
    for (int f = 0; f < 8; ++f) {
        const int col = f * 16 + m;
        const float bb = biasp[col];
        #pragma unroll
        for (int r = 0; r < 4; ++r)
            proj_v[(size_t)(row0 + kg * 4 + r) * 128 + col] = f2bf(acc[f][r] + bb);
    }
    // offsets -> f32
    #pragma unroll
    for (int f = 8; f < 12; ++f) {
        const int col = f * 16 + m;
        const float bb = biasp[col];
        #pragma unroll
        for (int r = 0; r < 4; ++r)
            proj_s[(size_t)(row0 + kg * 4 + r) * SC + (col - 128)] = acc[f][r] + bb;
    }
    // attn logits -> softmax -> f32 weights
    #pragma unroll
    for (int f = 12; f < 14; ++f) {
        const float bb = biasp[f * 16 + m];
        #pragma unroll
        for (int r = 0; r < 4; ++r) {
            float v = acc[f][r] + bb;
            float mx = v;
            mx = fmaxf(mx, swzx<1>(mx));
            mx = fmaxf(mx, swzx<2>(mx));
            mx = fmaxf(mx, swzx<4>(mx));
            float ex = __expf(v - mx);
            float sm = ex;
            sm += swzx<1>(sm); sm += swzx<2>(sm); sm += swzx<4>(sm);
            const float wp = ex / sm;
            proj_s[(size_t)(row0 + kg * 4 + r) * SC + 64 + (f - 12) * 16 + m] = wp;
        }
    }
}

// ---------------------------------------------------------------------------
// Deformable sampling: one wave per (b, n), all 4 heads in-loop.
// lane = d4*8 + p  (p = point in bits 0..2 -> reduce = xor swizzle 1/2/4;
// d4 = 4 head-dim elems). Grid (50,200,2): i = gather-fast dim (blockIdx.x*4
// + wid), j = blockIdx.y, b = blockIdx.z — no integer divisions anywhere.
// Softmax weights are precomputed by vsa_k_proj.
// ---------------------------------------------------------------------------
__global__ __launch_bounds__(256) void vsa_k_sample(
    const ushort* __restrict__ proj_v, const float* __restrict__ proj_s,
    ushort* __restrict__ tmp)
{
    const int lane = threadIdx.x & 63;
    const int wid  = threadIdx.x >> 6;
    const int p  = lane & 7;
    const int d4 = lane >> 3;           // 0..7

    const int i = blockIdx.x * 4 + wid; // 0..199 (fast: gather rows adjacent)
    const int j = blockIdx.y;           // 0..199
    const int b = blockIdx.z;
    const int n = i * X + j;
    const size_t bn = (size_t)b * N + n;

    const float* srow = proj_s + bn * SC;
    const char*  vb   = (const char*)(proj_v + (size_t)b * N * 128);
    const float fi = (float)i, fj = (float)j;
    const int dbyte = d4 * 8;

    #pragma unroll
    for (int h = 0; h < H; ++h) {
        const float wp  = srow[64 + h * 8 + p];
        const float2 off = *(const float2*)(srow + (h * 8 + p) * 2);

        const float ixf = fi + off.x;
        const float iyf = fj + off.y;
        const float x0f = floorf(ixf), y0f = floorf(iyf);
        const float lx = ixf - x0f,   ly = iyf - y0f;
        const int x0 = (int)x0f, y0 = (int)y0f;
        const int x1 = x0 + 1,  y1 = y0 + 1;
        const int xc0 = min(max(x0, 0), X - 1), xc1 = min(max(x1, 0), X - 1);
        const int yc0 = min(max(y0, 0), Z - 1), yc1 = min(max(y1, 0), Z - 1);

        const float wx0 = ((unsigned)x0 < (unsigned)X) ? (1.f - lx) * wp : 0.f;
        const float wx1 = ((unsigned)x1 < (unsigned)X) ? lx * wp : 0.f;
        const float wy0 = ((unsigned)y0 < (unsigned)Z) ? (1.f - ly) : 0.f;
        const float wy1 = ((unsigned)y1 < (unsigned)Z) ? ly : 0.f;
        const float w00 = wx0 * wy0, w10 = wx1 * wy0;
        const float w01 = wx0 * wy1, w11 = wx1 * wy1;

        const int rb0 = yc0 * X, rb1 = yc1 * X;
        const int hb  = h * 64 + dbyte;
        const int o00 = (rb0 + xc0) * 256 + hb;
        const int o10 = (rb0 + xc1) * 256 + hb;
        const int o01 = (rb1 + xc0) * 256 + hb;
        const int o11 = (rb1 + xc1) * 256 + hb;

        const uint2 c00 = *(const uint2*)(vb + o00);
        const uint2 c10 = *(const uint2*)(vb + o10);
        const uint2 c01 = *(const uint2*)(vb + o01);
        const uint2 c11 = *(const uint2*)(vb + o11);

        float a0 = w00 * bflo(c00.x) + w10 * bflo(c10.x) + w01 * bflo(c01.x) + w11 * bflo(c11.x);
        float a1 = w00 * bfhi(c00.x) + w10 * bfhi(c10.x) + w01 * bfhi(c01.x) + w11 * bfhi(c11.x);
        float a2 = w00 * bflo(c00.y) + w10 * bflo(c10.y) + w01 * bflo(c01.y) + w11 * bflo(c11.y);
        float a3 = w00 * bfhi(c00.y) + w10 * bfhi(c10.y) + w01 * bfhi(c01.y) + w11 * bfhi(c11.y);

        // reduce over the 8 points: p sits in lane bits 0..2
        a0 += swzx<1>(a0); a1 += swzx<1>(a1); a2 += swzx<1>(a2); a3 += swzx<1>(a3);
        a0 += swzx<2>(a0); a1 += swzx<2>(a1); a2 += swzx<2>(a2); a3 += swzx<2>(a3);
        a0 += swzx<4>(a0); a1 += swzx<4>(a1); a2 += swzx<4>(a2); a3 += swzx<4>(a3);

        if (p == 0) {
            uint2 o;
            o.x = packbf(a0, a1);
            o.y = packbf(a2, a3);
            *(uint2*)(tmp + bn * 128 + h * 32 + d4 * 4) = o;
        }
    }
}

// ---------------------------------------------------------------------------
// Output GEMM (MFMA, no LDS) + residual: out = tmp @ W12 + b12 + Q.
// ---------------------------------------------------------------------------
__global__ __launch_bounds__(256) void vsa_k_out(
    const ushort* __restrict__ tmp, const ushort* __restrict__ wtp2,
    const float* __restrict__ bias2, const float* __restrict__ Q,
    float* __restrict__ out)
{
    const int lane = threadIdx.x & 63;
    const int wave = blockIdx.x * 4 + (threadIdx.x >> 6);
    const int row0 = wave * 16;
    const int m  = lane & 15;
    const int kg = lane >> 4;

    const ushort* ap = tmp + (size_t)(row0 + m) * 128 + kg * 8;

    f32x4 acc[NF_O];
    #pragma unroll
    for (int f = 0; f < NF_O; ++f) acc[f] = (f32x4){0.f, 0.f, 0.f, 0.f};

    #pragma unroll
    for (int ks = 0; ks < KS; ++ks) {
        short8 af = *(const short8*)(ap + ks * 32);
        const short8* wrow = (const short8*)wtp2 + ks * NF_O * 64 + lane;
        #pragma unroll
        for (int f = 0; f < NF_O; ++f)
            acc[f] = __builtin_amdgcn_mfma_f32_16x16x32_bf16(af, wrow[f * 64], acc[f], 0, 0, 0);
    }

    #pragma unroll
    for (int f = 0; f < NF_O; ++f) {
        const int col = f * 16 + m;
        const float bb = bias2[col];
        #pragma unroll
        for (int r = 0; r < 4; ++r) {
            const int row = row0 + kg * 4 + r;
            out[(size_t)row * 128 + col] = acc[f][r] + bb + Q[(size_t)row * 128 + col];
        }
    }
}

// ---------------------------------------------------------------------------
extern "C" void kernel_launch(void* const* d_in, const int* in_sizes, int n_in,
                              void* d_out, int out_size, void* d_ws, size_t ws_size,
                              hipStream_t stream) {
    const float* Q     = (const float*)d_in[0];
    const float* Wv    = (const float*)d_in[1];
    const float* bv    = (const float*)d_in[2];
    const float* Woff  = (const float*)d_in[3];
    const float* boff  = (const float*)d_in[4];
    const float* Wattn = (const float*)d_in[5];
    const float* battn = (const float*)d_in[6];
    const float* Wout1 = (const float*)d_in[7];
    const float* bout1 = (const float*)d_in[8];
    const float* Wout2 = (const float*)d_in[9];
    const float* bout2 = (const float*)d_in[10];
    float* out = (float*)d_out;

    // Workspace: proj_s f32[BN][96] | biasp[224] | b12[128] |
    //            proj_v bf16[BN][128] | tmp bf16[BN][128] | wtp | wtp2
    float*  proj_s = (float*)d_ws;
    float*  biasp  = proj_s + (size_t)BN * SC;
    float*  bias2  = biasp + 224;
    ushort* proj_v = (ushort*)(bias2 + 128);
    ushort* tmp    = proj_v + (size_t)BN * 128;
    ushort* wtp    = tmp + (size_t)BN * 128;
    ushort* wtp2   = wtp + (size_t)KS * NF_P * 64 * 8;

    constexpr int prep_n = KS * NF_P * 64 + KS * NF_O * 64 + 224 + 128; // 5984
    vsa_k_prep<<<(prep_n + 255) / 256, 256, 0, stream>>>(
        Wv, bv, Woff, boff, Wattn, battn, Wout1, bout1, Wout2, bout2,
        wtp, wtp2, biasp, bias2);
    vsa_k_proj<<<BN / 64, 256, 0, stream>>>(Q, wtp, biasp, proj_v, proj_s);
    vsa_k_sample<<<dim3(Z / 4, X, B), 256, 0, stream>>>(proj_v, proj_s, tmp);
    vsa_k_out<<<BN / 64, 256, 0, stream>>>(tmp, wtp2, bias2, Q, out);
}